// Round 2
// baseline (345.118 us; speedup 1.0000x reference)
//
#include <hip/hip_runtime.h>
#include <hip/hip_bf16.h>

// LSTM block, fused: gates GEMM [B,256]x[256,512] + activations + c_new
// + GEMM2 [B,128]x[128,128] + h_new. Inputs fp32, OUTPUTS FP32 (ref dtype).
// bf16 MFMA internally (tolerance 8.375e-2 permits), weights pre-converted in d_ws.

typedef __attribute__((ext_vector_type(8))) short bf16x8;   // 8 bf16 = 4 VGPRs
typedef __attribute__((ext_vector_type(4))) float f32x4;

static __device__ __forceinline__ unsigned short f2bf(float f) {
    unsigned int u = __builtin_bit_cast(unsigned int, f);
    u += 0x7FFFu + ((u >> 16) & 1u);      // RNE
    return (unsigned short)(u >> 16);
}

static __device__ __forceinline__ bf16x8 cvt8(f32x4 a, f32x4 b) {
    union { bf16x8 v; unsigned short u[8]; } r;
    r.u[0] = f2bf(a[0]); r.u[1] = f2bf(a[1]); r.u[2] = f2bf(a[2]); r.u[3] = f2bf(a[3]);
    r.u[4] = f2bf(b[0]); r.u[5] = f2bf(b[1]); r.u[6] = f2bf(b[2]); r.u[7] = f2bf(b[3]);
    return r.v;
}

static __device__ __forceinline__ float fsig(float x) {
    float e = __builtin_amdgcn_exp2f(-1.44269504f * x);
    return __builtin_amdgcn_rcpf(1.0f + e);
}
static __device__ __forceinline__ float ftanh(float x) {
    float e = __builtin_amdgcn_exp2f(2.8853900818f * x);
    return 1.0f - 2.0f * __builtin_amdgcn_rcpf(e + 1.0f);
}

// ---------------- weight prep: fp32 [K,N] -> bf16 transposed [N,K] ----------------
__global__ void prep_weights(const float* __restrict__ Wf, const float* __restrict__ Wi,
                             const float* __restrict__ Wc, const float* __restrict__ Wo,
                             const float* __restrict__ Wch,
                             unsigned short* __restrict__ WgT,   // [512][256]
                             unsigned short* __restrict__ WchT)  // [128][128]
{
    int tid = blockIdx.x * 256 + threadIdx.x;
    if (tid < 512 * 32) {
        int n  = tid >> 5;          // 0..511  (gate-major output col)
        int k0 = (tid & 31) * 8;    // 0..248
        const float* W = (n < 128) ? Wf : (n < 256) ? Wi : (n < 384) ? Wc : Wo;
        int nn = n & 127;
        union { bf16x8 v; unsigned short u[8]; } r;
#pragma unroll
        for (int i = 0; i < 8; ++i) r.u[i] = f2bf(W[(size_t)(k0 + i) * 128 + nn]);
        *(bf16x8*)(WgT + n * 256 + k0) = r.v;
    } else if (tid < 512 * 32 + 128 * 16) {
        int t  = tid - 512 * 32;
        int n  = t >> 4;            // 0..127
        int k0 = (t & 15) * 8;      // 0..120
        union { bf16x8 v; unsigned short u[8]; } r;
#pragma unroll
        for (int i = 0; i < 8; ++i) r.u[i] = f2bf(Wch[(size_t)(k0 + i) * 128 + n]);
        *(bf16x8*)(WchT + n * 128 + k0) = r.v;
    }
}

// ---------------- fused LSTM kernel: 64 rows per 256-thread block ----------------
__global__ __launch_bounds__(256, 2) void lstm_fused(
    const float* __restrict__ xg, const float* __restrict__ hg, const float* __restrict__ cg,
    const float* __restrict__ bfv, const float* __restrict__ biv,
    const float* __restrict__ bcv, const float* __restrict__ bov,
    const float* __restrict__ bchv,
    const unsigned short* __restrict__ WgT, const unsigned short* __restrict__ WchT,
    float* __restrict__ out, int nrows)
{
    // Blds (64 KB): GEMM1 B-tiles, then {WchT bf16 | c-input fp32}, then {h fp32 | c_new fp32}
    __shared__ unsigned short Blds[512 * 64];
    __shared__ unsigned short CnLds[64 * 128];   // 16 KB: bf16 c_new (GEMM2 A operand)

    const int tid  = threadIdx.x;
    const int wv   = tid >> 6;
    const int lane = tid & 63;
    const int l15  = lane & 15;
    const int lg   = lane >> 4;          // 0..3
    const int m0   = blockIdx.x * 64;

    f32x4 acc[32];
#pragma unroll
    for (int i = 0; i < 32; ++i) acc[i] = {0.f, 0.f, 0.f, 0.f};

    const int arow = m0 + wv * 16 + l15;           // A-operand row for this lane
    const float* xr = xg + (size_t)arow * 128;
    const float* hr = hg + (size_t)arow * 128;

    // ---- GEMM1: gates[64,512] = concat(x,h)[64,256] @ Wg[256,512], K-chunked by 64
    for (int kc = 0; kc < 4; ++kc) {
        if (kc) __syncthreads();
        {   // stage WgT[:, kc*64 .. +64) -> Blds[n][k], XOR-swizzled
            const int slot = tid & 7;
            const int nb   = tid >> 3;
#pragma unroll
            for (int it = 0; it < 16; ++it) {
                int n = it * 32 + nb;
                bf16x8 w = *(const bf16x8*)(WgT + n * 256 + kc * 64 + slot * 8);
                int byt = (n * 128 + slot * 16) ^ ((n & 7) << 4);
                *(bf16x8*)((char*)Blds + byt) = w;
            }
        }
        // A fragments for this K-chunk (global fp32 -> bf16 in-register)
        bf16x8 af[2];
#pragma unroll
        for (int ks = 0; ks < 2; ++ks) {
            int col = kc * 64 + ks * 32 + lg * 8;
            const float* s = (col < 128) ? (xr + col) : (hr + (col - 128));
            f32x4 v0 = *(const f32x4*)s;
            f32x4 v1 = *(const f32x4*)(s + 4);
            af[ks] = cvt8(v0, v1);
        }
        __syncthreads();
#pragma unroll
        for (int nt = 0; nt < 32; ++nt) {
#pragma unroll
            for (int ks = 0; ks < 2; ++ks) {
                int n   = nt * 16 + l15;
                int byt = (n * 128 + ks * 64 + lg * 16) ^ ((n & 7) << 4);
                bf16x8 b = *(const bf16x8*)((char*)Blds + byt);
                acc[nt] = __builtin_amdgcn_mfma_f32_16x16x32_bf16(af[ks], b, acc[nt], 0, 0, 0);
            }
        }
    }
    __syncthreads();   // all waves done reading Blds (GEMM1)

    // ---- stage: WchT bf16 -> Blds[0..32K), c-input fp32 tile -> Blds[32K..64K)
    {
        const int n  = tid >> 1;
        const int kh = (tid & 1) * 64;
#pragma unroll
        for (int it = 0; it < 8; ++it) {
            int k0 = kh + it * 8;
            bf16x8 w = *(const bf16x8*)(WchT + n * 128 + k0);
            int byt = (n * 256 + k0 * 2) ^ ((n & 15) << 4);
            *(bf16x8*)((char*)Blds + byt) = w;
        }
#pragma unroll
        for (int it = 0; it < 8; ++it) {
            int u   = it * 256 + tid;          // 16B unit: row=u>>5, block=u&31
            int row = u >> 5;
            int c4  = u & 31;
            f32x4 v = *(const f32x4*)(cg + (size_t)(m0 + row) * 128 + c4 * 4);
            int byt = 32768 + ((row * 512 + c4 * 16) ^ ((row & 15) << 4));
            *(f32x4*)((char*)Blds + byt) = v;
        }
    }
    __syncthreads();

    // ---- gate activations; c_new fp32 kept in regs, bf16 copy to CnLds for GEMM2
    f32x4 okeep[8], cnk[8];
    const int crow0 = wv * 16 + lg * 4;            // C-fragment row base (local)
#pragma unroll
    for (int j = 0; j < 8; ++j) {
        const int colg = j * 16 + l15;             // 0..127 within each gate
        const float bf_ = bfv[colg], bi_ = biv[colg], bc_ = bcv[colg], bo_ = bov[colg];
#pragma unroll
        for (int r = 0; r < 4; ++r) {
            int rowl = crow0 + r;
            int cb   = 32768 + ((rowl * 512 + colg * 4) ^ ((rowl & 15) << 4));
            float cval = *(const float*)((char*)Blds + cb);
            float f  = fsig(acc[j][r] + bf_);
            float i  = fsig(acc[8 + j][r] + bi_);
            float ct = ftanh(acc[16 + j][r] + bc_);
            float o  = fsig(acc[24 + j][r] + bo_);
            okeep[j][r] = o;
            float cn = f * cval + i * ct;
            cnk[j][r] = cn;
            int byt = (rowl * 256 + colg * 2) ^ ((rowl & 15) << 4);
            *(unsigned short*)((char*)CnLds + byt) = f2bf(cn);
        }
    }
    // a2 fragments: wave-local rows of CnLds (same wave wrote them; lgkmcnt orders)
    bf16x8 a2[4];
    {
        const int rl = wv * 16 + l15;
#pragma unroll
        for (int kt = 0; kt < 4; ++kt) {
            int byt = (rl * 256 + kt * 64 + lg * 16) ^ ((rl & 15) << 4);
            a2[kt] = *(const bf16x8*)((char*)CnLds + byt);
        }
    }

    // ---- GEMM2: t[64,128] = c_new @ Wch  (B from Blds[0..32K))
    f32x4 acc2[8];
#pragma unroll
    for (int i = 0; i < 8; ++i) acc2[i] = {0.f, 0.f, 0.f, 0.f};
#pragma unroll
    for (int nt = 0; nt < 8; ++nt) {
#pragma unroll
        for (int kt = 0; kt < 4; ++kt) {
            int n   = nt * 16 + l15;
            int byt = (n * 256 + kt * 64 + lg * 16) ^ ((n & 15) << 4);
            bf16x8 b = *(const bf16x8*)((char*)Blds + byt);
            acc2[nt] = __builtin_amdgcn_mfma_f32_16x16x32_bf16(a2[kt], b, acc2[nt], 0, 0, 0);
        }
    }
    __syncthreads();   // all waves done with WchT + c-input regions of Blds

    // ---- h fp32 -> Blds[0..32K), c_new fp32 -> Blds[32K..64K)
#pragma unroll
    for (int j = 0; j < 8; ++j) {
        int colg = j * 16 + l15;
        float bb = bchv[colg];
#pragma unroll
        for (int r = 0; r < 4; ++r) {
            int rowl = crow0 + r;
            float t  = ftanh(acc2[j][r] + bb);
            float hv = okeep[j][r] * t;
            int byt = (rowl * 512 + colg * 4) ^ ((rowl & 15) << 4);
            *(float*)((char*)Blds + byt)         = hv;
            *(float*)((char*)Blds + 32768 + byt) = cnk[j][r];
        }
    }
    __syncthreads();

    // ---- coalesced f32x4 stores: h then c (outputs concatenated flat, fp32)
    float* houtf = out + (size_t)m0 * 128;
    float* coutf = out + (size_t)nrows * 128 + (size_t)m0 * 128;
#pragma unroll
    for (int it = 0; it < 8; ++it) {
        int u   = it * 256 + tid;            // 16B unit
        int row = u >> 5;
        int off = (u & 31) * 16;
        int sb  = row * 512 + (off ^ ((row & 15) << 4));
        f32x4 hv = *(const f32x4*)((char*)Blds + sb);
        f32x4 cv = *(const f32x4*)((char*)Blds + 32768 + sb);
        *(f32x4*)(houtf + (size_t)u * 4) = hv;
        *(f32x4*)(coutf + (size_t)u * 4) = cv;
    }
}

extern "C" void kernel_launch(void* const* d_in, const int* in_sizes, int n_in,
                              void* d_out, int out_size, void* d_ws, size_t ws_size,
                              hipStream_t stream)
{
    const float* x   = (const float*)d_in[0];
    const float* h   = (const float*)d_in[1];
    const float* c   = (const float*)d_in[2];
    const float* Wf  = (const float*)d_in[3];
    const float* bf_ = (const float*)d_in[4];
    const float* Wi  = (const float*)d_in[5];
    const float* bi_ = (const float*)d_in[6];
    const float* Wc  = (const float*)d_in[7];
    const float* bc_ = (const float*)d_in[8];
    const float* Wo  = (const float*)d_in[9];
    const float* bo_ = (const float*)d_in[10];
    const float* Wch = (const float*)d_in[11];
    const float* bch = (const float*)d_in[12];

    unsigned short* WgT  = (unsigned short*)d_ws;         // 512*256 bf16
    unsigned short* WchT = WgT + 512 * 256;               // 128*128 bf16
    float* out = (float*)d_out;

    int nrows = in_sizes[0] / 128;                        // 262144

    prep_weights<<<dim3(72), dim3(256), 0, stream>>>(Wf, Wi, Wc, Wo, Wch, WgT, WchT);
    lstm_fused<<<dim3(nrows / 64), dim3(256), 0, stream>>>(
        x, h, c, bf_, bi_, bc_, bo_, bch, WgT, WchT, out, nrows);
}

// Round 3
// 196.552 us; speedup vs baseline: 1.7559x; 1.7559x over previous
//
#include <hip/hip_runtime.h>
#include <hip/hip_bf16.h>

// LSTM block, fused. Inputs fp32, outputs fp32. bf16 MFMA internally.
// Structure: 512-thread block, 128 rows. 8 waves, each a 64x128 tile of the
// gates GEMM (N' = gate-interleaved col permutation so the 4-gate elementwise
// is lane-local). Fragment-linear weight layouts (prep kernel) -> all hot LDS
// reads are contiguous 1KB wave reads. B staged via global_load_lds, dbuf.

typedef __attribute__((ext_vector_type(8))) short bf16x8;   // 8 bf16 = 4 VGPRs
typedef __attribute__((ext_vector_type(4))) float f32x4;

static __device__ __forceinline__ unsigned short f2bf(float f) {
    unsigned int u = __builtin_bit_cast(unsigned int, f);
    u += 0x7FFFu + ((u >> 16) & 1u);      // RNE
    return (unsigned short)(u >> 16);
}

static __device__ __forceinline__ bf16x8 cvt8(f32x4 a, f32x4 b) {
    union { bf16x8 v; unsigned short u[8]; } r;
    r.u[0] = f2bf(a[0]); r.u[1] = f2bf(a[1]); r.u[2] = f2bf(a[2]); r.u[3] = f2bf(a[3]);
    r.u[4] = f2bf(b[0]); r.u[5] = f2bf(b[1]); r.u[6] = f2bf(b[2]); r.u[7] = f2bf(b[3]);
    return r.v;
}

static __device__ __forceinline__ float fsig(float x) {
    float e = __builtin_amdgcn_exp2f(-1.44269504f * x);
    return __builtin_amdgcn_rcpf(1.0f + e);
}
static __device__ __forceinline__ float ftanh(float x) {
    float e = __builtin_amdgcn_exp2f(2.8853900818f * x);
    return 1.0f - 2.0f * __builtin_amdgcn_rcpf(e + 1.0f);
}

static __device__ __forceinline__ void gload16(const void* gsrc, void* ldst) {
    __builtin_amdgcn_global_load_lds(
        (const __attribute__((address_space(1))) unsigned int*)gsrc,
        (__attribute__((address_space(3))) unsigned int*)ldst,
        16, 0, 0);
}

// ---------------- weight prep: fragment-linear bf16 layouts ----------------
// WgF: gates weights, N'-permuted. Block (kc 0..7, nblk 0..31) of 64 lanes x 16B.
//   lane (l15,lg) holds col n' = nblk*16+l15, k = kc*32+lg*8 .. +8.
//   n' = (cg>>5)*128 + g*32 + (cg&31)  [g = gate, cg = within-gate col]
// WchF: block (nblk2 0..7, kt 0..3): lane holds col n = nblk2*16+l15, k = kt*32+lg*8.
__global__ void prep_weights(const float* __restrict__ Wf, const float* __restrict__ Wi,
                             const float* __restrict__ Wc, const float* __restrict__ Wo,
                             const float* __restrict__ Wch,
                             unsigned short* __restrict__ WgF,   // 512*256
                             unsigned short* __restrict__ WchF)  // 128*128
{
    int u = blockIdx.x * 256 + threadIdx.x;
    if (u < 16384) {
        int lane = u & 63, nb = (u >> 6) & 31, kc = u >> 11;
        int l15 = lane & 15, lg = lane >> 4;
        int np = nb * 16 + l15;                  // permuted col index
        int wv = np >> 7, g = (np >> 5) & 3, c5 = np & 31;
        int cg = wv * 32 + c5;                   // within-gate col
        int k0 = kc * 32 + lg * 8;
        const float* W = (g == 0) ? Wf : (g == 1) ? Wi : (g == 2) ? Wc : Wo;
        union { bf16x8 v; unsigned short s[8]; } r;
#pragma unroll
        for (int i = 0; i < 8; ++i) r.s[i] = f2bf(W[(size_t)(k0 + i) * 128 + cg]);
        *(bf16x8*)(WgF + (size_t)u * 8) = r.v;
    } else if (u < 16384 + 2048) {
        int u2 = u - 16384;
        int lane = u2 & 63, kt = (u2 >> 6) & 3, nb2 = u2 >> 8;
        int l15 = lane & 15, lg = lane >> 4;
        int n = nb2 * 16 + l15, k0 = kt * 32 + lg * 8;
        union { bf16x8 v; unsigned short s[8]; } r;
#pragma unroll
        for (int i = 0; i < 8; ++i) r.s[i] = f2bf(Wch[(size_t)(k0 + i) * 128 + n]);
        *(bf16x8*)(WchF + (size_t)u2 * 8) = r.v;
    }
}

// ---------------- fused LSTM kernel: 128 rows per 512-thread block ----------------
// LDS map (128 KB): A [0,64K) 64 blocks of 1KB (kc*8+rb); B0 [64K,96K); B1 [96K,128K)
// Epilogue reuse: A[0,32K) <- c_new exchange (32 blocks rb2*4+kt); B0 <- WchF.
__global__ __launch_bounds__(512, 2) void lstm_fused(
    const float* __restrict__ xg, const float* __restrict__ hg, const float* __restrict__ cg,
    const float* __restrict__ bfv, const float* __restrict__ biv,
    const float* __restrict__ bcv, const float* __restrict__ bov,
    const float* __restrict__ bchv,
    const unsigned short* __restrict__ WgF, const unsigned short* __restrict__ WchF,
    float* __restrict__ out, int nrows)
{
    __shared__ uint4 lds4[8192];                 // 128 KB
    char* lds = (char*)lds4;

    const int tid  = threadIdx.x;
    const int lane = tid & 63;
    const int wv   = tid >> 6;                   // 0..7
    const int wm   = wv & 1;                     // row half: rows wm*64..+64
    const int wn   = wv >> 1;                    // N' group: cols wn*128..+128
    const int l15  = lane & 15;
    const int lg   = lane >> 4;
    const long m0  = (long)blockIdx.x * 128;

    // biases (lane-local cols: cg = wn*32 + hb*16 + l15)
    float bfb[2], bib[2], bcb[2], bob[2], bchb[2];
#pragma unroll
    for (int hb = 0; hb < 2; ++hb) {
        int col = wn * 32 + hb * 16 + l15;
        bfb[hb] = bfv[col]; bib[hb] = biv[col]; bcb[hb] = bcv[col];
        bob[hb] = bov[col]; bchb[hb] = bchv[col];
    }

    // ---- stage A: concat(x,h)[128 rows][256] -> bf16 fragment blocks
#pragma unroll
    for (int j = 0; j < 8; ++j) {
        int u   = tid + 512 * j;                 // 4096 units of 8 elems
        int row = u >> 5, kg = u & 31, k0 = kg * 8;
        long grow = m0 + row;
        const float* s = (k0 < 128) ? (xg + grow * 128 + k0)
                                    : (hg + grow * 128 + (k0 - 128));
        f32x4 v0 = *(const f32x4*)s;
        f32x4 v1 = *(const f32x4*)(s + 4);
        int blk  = (kg >> 2) * 8 + (row >> 4);
        int slot = (kg & 3) * 16 + (row & 15);
        *(bf16x8*)(lds + blk * 1024 + slot * 16) = cvt8(v0, v1);
    }
    // ---- stage B chunk 0 (global_load_lds, linear)
    {
        const char* src = (const char*)(WgF);    // chunk 0
        char* dstb = lds + 65536;
        int o = wv * 1024 + lane * 16;
#pragma unroll
        for (int j = 0; j < 4; ++j)
            gload16(src + j * 8192 + o, dstb + j * 8192 + o);
    }
    __syncthreads();

    f32x4 acc[4][8];
#pragma unroll
    for (int a = 0; a < 4; ++a)
#pragma unroll
        for (int b = 0; b < 8; ++b) acc[a][b] = {0.f, 0.f, 0.f, 0.f};

    float creg[4][2][4];                         // c input [am][hb][r]

    // ---- GEMM1 main loop: 8 K-chunks of 32, double-buffered B
    for (int kc = 0; kc < 8; ++kc) {
        if (kc < 7) {                            // prefetch next chunk
            const char* src = (const char*)(WgF + (size_t)(kc + 1) * 16384);
            char* dstb = lds + 65536 + ((kc + 1) & 1) * 32768;
            int o = wv * 1024 + lane * 16;
#pragma unroll
            for (int j = 0; j < 4; ++j)
                gload16(src + j * 8192 + o, dstb + j * 8192 + o);
        }
        if (kc == 7) {
            // stage Wch -> B0 (free since chunk 6's barrier) + c input -> regs
            char* dstb = lds + 65536;
            int o = wv * 1024 + lane * 16;
#pragma unroll
            for (int j = 0; j < 4; ++j)
                gload16((const char*)WchF + j * 8192 + o, dstb + j * 8192 + o);
#pragma unroll
            for (int am = 0; am < 4; ++am)
#pragma unroll
                for (int hb = 0; hb < 2; ++hb)
#pragma unroll
                    for (int r = 0; r < 4; ++r) {
                        long grow = m0 + wm * 64 + am * 16 + lg * 4 + r;
                        creg[am][hb][r] = cg[grow * 128 + wn * 32 + hb * 16 + l15];
                    }
        }
        // A fragments (4 contiguous 1KB wave reads)
        bf16x8 af[4];
#pragma unroll
        for (int am = 0; am < 4; ++am)
            af[am] = *(const bf16x8*)(lds + (kc * 8 + wm * 4 + am) * 1024 + lane * 16);
        // B fragments + MFMA
        char* bbase = lds + 65536 + (kc & 1) * 32768 + wn * 8192;
#pragma unroll
        for (int bn = 0; bn < 8; ++bn) {
            bf16x8 bfrag = *(const bf16x8*)(bbase + bn * 1024 + lane * 16);
#pragma unroll
            for (int am = 0; am < 4; ++am)
                acc[am][bn] = __builtin_amdgcn_mfma_f32_16x16x32_bf16(af[am], bfrag, acc[am][bn], 0, 0, 0);
        }
        __syncthreads();                         // next-chunk loads landed during MFMAs
    }

    // ---- elementwise: gates -> c_new (fp32 regs + bf16 exchange to A-region)
    float cn[4][2][4];
#pragma unroll
    for (int am = 0; am < 4; ++am)
#pragma unroll
        for (int hb = 0; hb < 2; ++hb)
#pragma unroll
            for (int r = 0; r < 4; ++r) {
                float f  = fsig(acc[am][0 + hb][r] + bfb[hb]);
                float i  = fsig(acc[am][2 + hb][r] + bib[hb]);
                float ct = ftanh(acc[am][4 + hb][r] + bcb[hb]);
                float cv = f * creg[am][hb][r] + i * ct;
                cn[am][hb][r] = cv;
                int blk  = (wm * 4 + am) * 4 + wn;           // (rb2, kt=wn)
                int slot = (hb * 2 + (l15 >> 3)) * 16 + (lg * 4 + r);
                *(unsigned short*)(lds + blk * 1024 + slot * 16 + (l15 & 7) * 2) = f2bf(cv);
            }
    __syncthreads();                             // c_new visible; Wch already staged

    // ---- GEMM2: t[128,128] = c_new @ Wch ; wave tile 64 rows x 32 cols
    f32x4 acc2[4][2];
#pragma unroll
    for (int a = 0; a < 4; ++a) { acc2[a][0] = {0.f,0.f,0.f,0.f}; acc2[a][1] = {0.f,0.f,0.f,0.f}; }
#pragma unroll
    for (int kt = 0; kt < 4; ++kt) {
        bf16x8 a2[4];
#pragma unroll
        for (int m = 0; m < 4; ++m)
            a2[m] = *(const bf16x8*)(lds + ((wm * 4 + m) * 4 + kt) * 1024 + lane * 16);
#pragma unroll
        for (int n2 = 0; n2 < 2; ++n2) {
            bf16x8 b2 = *(const bf16x8*)(lds + 65536 + ((wn * 2 + n2) * 4 + kt) * 1024 + lane * 16);
#pragma unroll
            for (int m = 0; m < 4; ++m)
                acc2[m][n2] = __builtin_amdgcn_mfma_f32_16x16x32_bf16(a2[m], b2, acc2[m][n2], 0, 0, 0);
        }
    }

    // ---- h = o * tanh(t + bch); store h and c_new (fp32)
    float* hout = out;
    float* cout = out + (size_t)nrows * 128;
#pragma unroll
    for (int am = 0; am < 4; ++am)
#pragma unroll
        for (int hb = 0; hb < 2; ++hb)
#pragma unroll
            for (int r = 0; r < 4; ++r) {
                long grow = m0 + wm * 64 + am * 16 + lg * 4 + r;
                int col = wn * 32 + hb * 16 + l15;
                float o  = fsig(acc[am][6 + hb][r] + bob[hb]);
                float hv = o * ftanh(acc2[am][hb][r] + bchb[hb]);
                hout[grow * 128 + col] = hv;
                cout[grow * 128 + col] = cn[am][hb][r];
            }
}

extern "C" void kernel_launch(void* const* d_in, const int* in_sizes, int n_in,
                              void* d_out, int out_size, void* d_ws, size_t ws_size,
                              hipStream_t stream)
{
    const float* x   = (const float*)d_in[0];
    const float* h   = (const float*)d_in[1];
    const float* c   = (const float*)d_in[2];
    const float* Wf  = (const float*)d_in[3];
    const float* bf_ = (const float*)d_in[4];
    const float* Wi  = (const float*)d_in[5];
    const float* bi_ = (const float*)d_in[6];
    const float* Wc  = (const float*)d_in[7];
    const float* bc_ = (const float*)d_in[8];
    const float* Wo  = (const float*)d_in[9];
    const float* bo_ = (const float*)d_in[10];
    const float* Wch = (const float*)d_in[11];
    const float* bch = (const float*)d_in[12];

    unsigned short* WgF  = (unsigned short*)d_ws;         // 512*256 bf16 fragment-linear
    unsigned short* WchF = WgF + 512 * 256;               // 128*128 bf16 fragment-linear
    float* out = (float*)d_out;

    int nrows = in_sizes[0] / 128;                        // 262144

    prep_weights<<<dim3(72), dim3(256), 0, stream>>>(Wf, Wi, Wc, Wo, Wch, WgF, WchF);
    lstm_fused<<<dim3(nrows / 128), dim3(512), 0, stream>>>(
        x, h, c, bf_, bi_, bc_, bo_, bch, WgF, WchF, out, nrows);
}